// Round 14
// baseline (865.682 us; speedup 1.0000x reference)
//
#include <hip/hip_runtime.h>
#include <hip/hip_bf16.h>
#include <stdint.h>

#define TN 4096      // tokens (B*S)
#define DI 4096      // input dim
#define DH 1376      // GLU hidden dim
#define DHP 1408     // padded hidden (22*64, 44*32)
#define DO 4096      // output dim
#define NE 8         // experts
#define NPAIR 8192   // TN * K

typedef unsigned short u16;
typedef __bf16 bf16x8 __attribute__((ext_vector_type(8)));
typedef float f32x4 __attribute__((ext_vector_type(4)));
typedef uint32_t u32x4 __attribute__((ext_vector_type(4)));

__device__ __forceinline__ uint32_t pack2bf(float a, float b) {
    union { float f; uint32_t u; } ua, ub;
    ua.f = a; ub.f = b;
    uint32_t lo = (ua.u + 0x7fffu + ((ua.u >> 16) & 1u)) >> 16;
    uint32_t hi = (ub.u + 0x7fffu + ((ub.u >> 16) & 1u)) >> 16;
    return lo | (hi << 16);
}
__device__ __forceinline__ u16 f2bf(float a) {
    union { float f; uint32_t u; } ua; ua.f = a;
    return (u16)((ua.u + 0x7fffu + ((ua.u >> 16) & 1u)) >> 16);
}
__device__ __forceinline__ void gload16(const void* g, void* l) {
    __builtin_amdgcn_global_load_lds(
        (const __attribute__((address_space(1))) void*)g,
        (__attribute__((address_space(3))) void*)l, 16, 0, 0);
}
#define MEMFENCE() asm volatile("" ::: "memory")

// ---------------- fused: weight convert (bulk BW) + gate (compute) ----------------
__global__ __launch_bounds__(256) void k_cvt_gate(
    const float* __restrict__ x, const float* __restrict__ gw,
    const float* __restrict__ wg, const float* __restrict__ wu,
    const float* __restrict__ wd, const float* __restrict__ bd,
    u16* __restrict__ x16, u16* __restrict__ wg16, u16* __restrict__ wu16,
    u16* __restrict__ wd16,
    int* __restrict__ tke, float* __restrict__ tks,
    int* __restrict__ cnt, float* __restrict__ imp)
{
    int tid = threadIdx.x;
    if (blockIdx.x < TN) {
        int t = blockIdx.x;
        const float* xr = x + (size_t)t * DI;
        double acc[NE];
#pragma unroll
        for (int e = 0; e < NE; ++e) acc[e] = 0.0;
#pragma unroll
        for (int j = 0; j < 4; ++j) {
            int i4 = (j * 256 + tid) * 4;
            float4 xv = *(const float4*)(xr + i4);
            uint2 p; p.x = pack2bf(xv.x, xv.y); p.y = pack2bf(xv.z, xv.w);
            *(uint2*)(x16 + (size_t)t * DI + i4) = p;
#pragma unroll
            for (int e = 0; e < NE; ++e) {
                float4 wv = *(const float4*)(gw + (size_t)e * DI + i4);
                acc[e] = fma((double)xv.x, (double)wv.x, acc[e]);
                acc[e] = fma((double)xv.y, (double)wv.y, acc[e]);
                acc[e] = fma((double)xv.z, (double)wv.z, acc[e]);
                acc[e] = fma((double)xv.w, (double)wv.w, acc[e]);
            }
        }
#pragma unroll
        for (int o = 32; o > 0; o >>= 1)
#pragma unroll
            for (int e = 0; e < NE; ++e) acc[e] += __shfl_down(acc[e], o, 64);
        __shared__ double lred[4][NE];
        if ((tid & 63) == 0)
#pragma unroll
            for (int e = 0; e < NE; ++e) lred[tid >> 6][e] = acc[e];
        __syncthreads();
        if (tid == 0) {
            double lg[NE];
#pragma unroll
            for (int e = 0; e < NE; ++e) lg[e] = lred[0][e] + lred[1][e] + lred[2][e] + lred[3][e];
            int e1 = 0;
            for (int e = 1; e < NE; ++e) if (lg[e] > lg[e1]) e1 = e;
            int e2 = -1;
            for (int e = 0; e < NE; ++e) { if (e == e1) continue; if (e2 < 0 || lg[e] > lg[e2]) e2 = e; }
            float d = (float)(lg[e2] - lg[e1]);
            float ed = expf(d);
            float s1 = 1.0f / (1.0f + ed);
            float s2 = ed / (1.0f + ed);
            tke[2 * t] = e1; tke[2 * t + 1] = e2;
            tks[2 * t] = s1; tks[2 * t + 1] = s2;
            atomicAdd(&cnt[e1], 1); atomicAdd(&cnt[e2], 1);
            unsafeAtomicAdd(&imp[e1], s1); unsafeAtomicAdd(&imp[e2], s2);
        }
        return;
    }
    int i = (blockIdx.x - TN) * 256 + tid;
    if (i < 11272192) {
        const float* src = (i < 5636096) ? wg : wu;
        u16* dst = (i < 5636096) ? wg16 : wu16;
        int j = (i < 5636096) ? i : i - 5636096;
        const float4* s = (const float4*)(src + (size_t)j * 8);
        float4 a = s[0], b = s[1];
        u32x4 v = {pack2bf(a.x, a.y), pack2bf(a.z, a.w), pack2bf(b.x, b.y), pack2bf(b.z, b.w)};
        *(u32x4*)(dst + (size_t)j * 8) = v;
    } else {
        int j = i - 11272192;
        if (j >= 5767168) return;
        int row = j / 176, c8 = (j % 176) * 8;
        u32x4 v = {0u, 0u, 0u, 0u};
        if (c8 < DH) {
            const float4* s = (const float4*)(wd + (size_t)row * DH + c8);
            float4 a = s[0], b = s[1];
            v = (u32x4){pack2bf(a.x, a.y), pack2bf(a.z, a.w), pack2bf(b.x, b.y), pack2bf(b.z, b.w)};
        } else if (c8 == DH) {
            v.x = (uint32_t)f2bf(bd[row]);   // bias fold: pairs with inter col 1376 = score
        }
        *(u32x4*)(wd16 + (size_t)row * DHP + c8) = v;
    }
}

// ---------------- scatter + finalize (off/loss) ----------------
__global__ __launch_bounds__(256) void k_scatter_fin(
    const int* __restrict__ tke, const float* __restrict__ tks,
    const int* __restrict__ cnt, const float* __restrict__ imp,
    int* __restrict__ off, int* __restrict__ fill,
    int* __restrict__ tok, float* __restrict__ sc, float* __restrict__ loss_out)
{
    int loc[NE]; int o = 0;
#pragma unroll
    for (int e = 0; e < NE; ++e) { loc[e] = o; o += cnt[e]; }
    if (blockIdx.x == 0 && threadIdx.x == 0) {
#pragma unroll
        for (int e = 0; e < NE; ++e) off[e] = loc[e];
        float m1 = 0.f, m2 = 0.f;
        for (int e = 0; e < NE; ++e) { m1 += imp[e]; m2 += (float)cnt[e]; }
        m1 *= 0.125f; m2 *= 0.125f;
        float v1 = 0.f, v2 = 0.f;
        for (int e = 0; e < NE; ++e) {
            float d1 = imp[e] - m1, d2 = (float)cnt[e] - m2;
            v1 += d1 * d1; v2 += d2 * d2;
        }
        v1 /= 7.0f; v2 /= 7.0f;
        *loss_out = 0.01f * (v1 / (m1 * m1 + 1e-10f) + v2 / (m2 * m2 + 1e-10f));
    }
    int t = blockIdx.x * 256 + threadIdx.x;
    if (t >= TN) return;
#pragma unroll
    for (int k = 0; k < 2; ++k) {
        int e = tke[2 * t + k];
        int pos = loc[e] + atomicAdd(&fill[e], 1);
        tok[pos] = t; sc[pos] = tks[2 * t + k];
    }
}

// ============ small-block GEMMs: 128-thr / 2-wave, tile 128 x 64 ============
// Rationale (r13 post-mortem): 256-thr 128x128 tiles gave only 704 active
// blocks -> OccupancyPercent 14% (straggler round at <40% load). Same
// per-wave economics at half the block size doubles block count; LDS
// 32KB (s1) / 24KB (s2) -> 4-6 blocks/CU. Same 4-slot XOR swizzle (phys
// slot p of row r holds logical p ^ ((r>>1)&3)), rule-21 both-sides,
// wave-uniform gload_lds dests, r8 counted-vmcnt schedule.

// ---------------- stage-1: fused GLU GEMM ----------------
__global__ __launch_bounds__(128, 2) void k_stage1s(
    const u16* __restrict__ x16,
    const u16* __restrict__ wg16, const u16* __restrict__ wu16,
    const float* __restrict__ bg, const float* __restrict__ bu,
    const int* __restrict__ cnt, const int* __restrict__ off,
    const int* __restrict__ tok, const float* __restrict__ sc,
    u16* __restrict__ inter)
{
    int e = blockIdx.x & 7;               // expert -> XCD affinity
    int ce = cnt[e];
    int rows0 = (blockIdx.x >> 3) * 128;
    if (rows0 >= ce) return;
    int oe = off[e];
    int h0 = blockIdx.y * 64;
    int tid = threadIdx.x;

    __shared__ u16 As0[128 * 32]; __shared__ u16 As1[128 * 32];   // 8KB each
    __shared__ u16 Gs0[64 * 32];  __shared__ u16 Gs1[64 * 32];    // 4KB each
    __shared__ u16 Us0[64 * 32];  __shared__ u16 Us1[64 * 32];    // total 32KB

    int lane = tid & 63, wid2 = tid >> 6;       // 2 waves
    int swz = ((lane & 3) ^ ((lane >> 3) & 3)) * 8;

    // A: load j covers rows j*32 + wid2*16 + (lane>>2), phys slot lane&3
    const u16* ab[4];
#pragma unroll
    for (int j = 0; j < 4; ++j) {
        int rowA = j * 32 + wid2 * 16 + (lane >> 2);
        int rg = oe + min(rows0 + rowA, ce - 1);
        ab[j] = x16 + (size_t)tok[rg] * DI + swz;
    }
    // G/U: load c covers rows (2*wid2+c)*16 + (lane>>2)
    const u16* gb[2]; const u16* ub[2];
#pragma unroll
    for (int c = 0; c < 2; ++c) {
        int rowG = (2 * wid2 + c) * 16 + (lane >> 2);
        int hr = min(h0 + rowG, DH - 1);
        gb[c] = wg16 + ((size_t)e * DH + hr) * DI + swz;
        ub[c] = wu16 + ((size_t)e * DH + hr) * DI + swz;
    }

    int l15 = lane & 15;
    int colb = (((lane >> 4) ^ ((lane >> 1) & 3)) & 3) * 8;
    int rA = wid2 * 64 + l15;                   // + m*16
    int rB = l15;                                // + n*16

    f32x4 accg[4][4], accu[4][4];
    f32x4 vz = {0.f, 0.f, 0.f, 0.f};
#pragma unroll
    for (int m = 0; m < 4; ++m)
#pragma unroll
        for (int n = 0; n < 4; ++n) { accg[m][n] = vz; accu[m][n] = vz; }

#define S1_STAGE(A_, G_, U_, K0)                                     \
    do {                                                             \
        _Pragma("unroll")                                            \
        for (int j = 0; j < 4; ++j)                                  \
            gload16(ab[j] + (K0), &A_[j * 1024 + wid2 * 512]);       \
        _Pragma("unroll")                                            \
        for (int c = 0; c < 2; ++c) {                                \
            gload16(gb[c] + (K0), &G_[(2 * wid2 + c) * 512]);        \
            gload16(ub[c] + (K0), &U_[(2 * wid2 + c) * 512]);        \
        }                                                            \
    } while (0)

#define S1_COMPUTE(A_, G_, U_)                                       \
    do {                                                             \
        bf16x8 a[4], g[4], u[4];                                     \
        _Pragma("unroll")                                            \
        for (int m = 0; m < 4; ++m)                                  \
            a[m] = *(const bf16x8*)&A_[(rA + m * 16) * 32 + colb];   \
        _Pragma("unroll")                                            \
        for (int n = 0; n < 4; ++n) {                                \
            g[n] = *(const bf16x8*)&G_[(rB + n * 16) * 32 + colb];   \
            u[n] = *(const bf16x8*)&U_[(rB + n * 16) * 32 + colb];   \
        }                                                            \
        __builtin_amdgcn_s_setprio(1);                               \
        _Pragma("unroll")                                            \
        for (int m = 0; m < 4; ++m)                                  \
            _Pragma("unroll")                                        \
            for (int n = 0; n < 4; ++n) {                            \
                accg[m][n] = __builtin_amdgcn_mfma_f32_16x16x32_bf16(a[m], g[n], accg[m][n], 0, 0, 0); \
                accu[m][n] = __builtin_amdgcn_mfma_f32_16x16x32_bf16(a[m], u[n], accu[m][n], 0, 0, 0); \
            }                                                        \
        __builtin_amdgcn_s_setprio(0);                               \
    } while (0)

    const int NT = DI / 32;        // 128, even
    S1_STAGE(As0, Gs0, Us0, 0);
    S1_STAGE(As1, Gs1, Us1, 32);

    for (int kt = 0; kt < NT - 2; kt += 2) {
        asm volatile("s_waitcnt vmcnt(8)" ::: "memory");
        __builtin_amdgcn_s_barrier();
        MEMFENCE();
        S1_COMPUTE(As0, Gs0, Us0);
        __builtin_amdgcn_s_barrier();
        MEMFENCE();
        S1_STAGE(As0, Gs0, Us0, (kt + 2) * 32);
        asm volatile("s_waitcnt vmcnt(8)" ::: "memory");
        __builtin_amdgcn_s_barrier();
        MEMFENCE();
        S1_COMPUTE(As1, Gs1, Us1);
        __builtin_amdgcn_s_barrier();
        MEMFENCE();
        S1_STAGE(As1, Gs1, Us1, (kt + 3) * 32);
    }
    asm volatile("s_waitcnt vmcnt(8)" ::: "memory");
    __builtin_amdgcn_s_barrier();
    MEMFENCE();
    S1_COMPUTE(As0, Gs0, Us0);
    asm volatile("s_waitcnt vmcnt(0)" ::: "memory");
    __builtin_amdgcn_s_barrier();
    MEMFENCE();
    S1_COMPUTE(As1, Gs1, Us1);
#undef S1_STAGE
#undef S1_COMPUTE

    // epilogue: bias + silu + score-fold; col DH carries score (bias fold)
    int rmax = ce - rows0;
    float bgv[4], buv[4];
    int hc[4]; bool hok[4];
#pragma unroll
    for (int n = 0; n < 4; ++n) {
        hc[n] = h0 + n * 16 + l15;
        hok[n] = hc[n] < DH;
        bgv[n] = hok[n] ? bg[e * DH + hc[n]] : 0.f;
        buv[n] = hok[n] ? bu[e * DH + hc[n]] : 0.f;
    }
#pragma unroll
    for (int m = 0; m < 4; ++m) {
#pragma unroll
        for (int r = 0; r < 4; ++r) {
            int rl = wid2 * 64 + m * 16 + (lane >> 4) * 4 + r;
            if (rl < rmax) {
                int rg = oe + rows0 + rl;
                float s = sc[rg];
                size_t rowb = (size_t)rg * DHP;
#pragma unroll
                for (int n = 0; n < 4; ++n) {
                    float v = 0.f;
                    if (hok[n]) {
                        float gv = accg[m][n][r] + bgv[n];
                        float uv = accu[m][n][r] + buv[n];
                        float sig = 1.0f / (1.0f + __expf(-gv));
                        v = s * gv * sig * uv;
                    } else if (hc[n] == DH) {
                        v = s;
                    }
                    inter[rowb + hc[n]] = f2bf(v);
                }
            }
        }
    }
}

// ---------------- stage-2: down-proj GEMM + atomic scatter ----------------
__global__ __launch_bounds__(128, 3) void k_stage2s(
    const u16* __restrict__ inter, const u16* __restrict__ wd16,
    const int* __restrict__ cnt, const int* __restrict__ off,
    const int* __restrict__ tok, float* __restrict__ y)
{
    int e = blockIdx.x & 7;
    int ce = cnt[e];
    int rows0 = (blockIdx.x >> 3) * 128;
    if (rows0 >= ce) return;
    int oe = off[e];
    int o0 = blockIdx.y * 64;
    int tid = threadIdx.x;

    __shared__ u16 As0[128 * 32]; __shared__ u16 As1[128 * 32];   // 8KB each
    __shared__ u16 Bs0[64 * 32];  __shared__ u16 Bs1[64 * 32];    // 4KB each; total 24KB

    int lane = tid & 63, wid2 = tid >> 6;
    int swz = ((lane & 3) ^ ((lane >> 3) & 3)) * 8;

    const u16* ab[4];
#pragma unroll
    for (int j = 0; j < 4; ++j) {
        int rowA = j * 32 + wid2 * 16 + (lane >> 2);
        int ar = min(oe + rows0 + rowA, NPAIR - 1);
        ab[j] = inter + (size_t)ar * DHP + swz;
    }
    const u16* bb[2];
#pragma unroll
    for (int c = 0; c < 2; ++c) {
        int rowB = (2 * wid2 + c) * 16 + (lane >> 2);
        bb[c] = wd16 + ((size_t)e * DO + (o0 + rowB)) * DHP + swz;
    }

    int l15 = lane & 15;
    int colb = (((lane >> 4) ^ ((lane >> 1) & 3)) & 3) * 8;
    int rA = wid2 * 64 + l15;
    int rB = l15;

    f32x4 acc[4][4];
    f32x4 vz = {0.f, 0.f, 0.f, 0.f};
#pragma unroll
    for (int m = 0; m < 4; ++m)
#pragma unroll
        for (int n = 0; n < 4; ++n) acc[m][n] = vz;

#define S2_STAGE(A_, B_, K0)                                         \
    do {                                                             \
        _Pragma("unroll")                                            \
        for (int j = 0; j < 4; ++j)                                  \
            gload16(ab[j] + (K0), &A_[j * 1024 + wid2 * 512]);       \
        _Pragma("unroll")                                            \
        for (int c = 0; c < 2; ++c)                                  \
            gload16(bb[c] + (K0), &B_[(2 * wid2 + c) * 512]);        \
    } while (0)

#define S2_COMPUTE(A_, B_)                                           \
    do {                                                             \
        bf16x8 a[4], b[4];                                           \
        _Pragma("unroll")                                            \
        for (int m = 0; m < 4; ++m)                                  \
            a[m] = *(const bf16x8*)&A_[(rA + m * 16) * 32 + colb];   \
        _Pragma("unroll")                                            \
        for (int n = 0; n < 4; ++n)                                  \
            b[n] = *(const bf16x8*)&B_[(rB + n * 16) * 32 + colb];   \
        __builtin_amdgcn_s_setprio(1);                               \
        _Pragma("unroll")                                            \
        for (int m = 0; m < 4; ++m)                                  \
            _Pragma("unroll")                                        \
            for (int n = 0; n < 4; ++n)                              \
                acc[m][n] = __builtin_amdgcn_mfma_f32_16x16x32_bf16(a[m], b[n], acc[m][n], 0, 0, 0); \
        __builtin_amdgcn_s_setprio(0);                               \
    } while (0)

    const int NT = DHP / 32;       // 44, even
    S2_STAGE(As0, Bs0, 0);
    S2_STAGE(As1, Bs1, 32);

    for (int kt = 0; kt < NT - 2; kt += 2) {
        asm volatile("s_waitcnt vmcnt(6)" ::: "memory");
        __builtin_amdgcn_s_barrier();
        MEMFENCE();
        S2_COMPUTE(As0, Bs0);
        __builtin_amdgcn_s_barrier();
        MEMFENCE();
        S2_STAGE(As0, Bs0, (kt + 2) * 32);
        asm volatile("s_waitcnt vmcnt(6)" ::: "memory");
        __builtin_amdgcn_s_barrier();
        MEMFENCE();
        S2_COMPUTE(As1, Bs1);
        __builtin_amdgcn_s_barrier();
        MEMFENCE();
        S2_STAGE(As1, Bs1, (kt + 3) * 32);
    }
    asm volatile("s_waitcnt vmcnt(6)" ::: "memory");
    __builtin_amdgcn_s_barrier();
    MEMFENCE();
    S2_COMPUTE(As0, Bs0);
    asm volatile("s_waitcnt vmcnt(0)" ::: "memory");
    __builtin_amdgcn_s_barrier();
    MEMFENCE();
    S2_COMPUTE(As1, Bs1);
#undef S2_STAGE
#undef S2_COMPUTE

    int rmax = ce - rows0;
#pragma unroll
    for (int m = 0; m < 4; ++m) {
#pragma unroll
        for (int r = 0; r < 4; ++r) {
            int rl = wid2 * 64 + m * 16 + (lane >> 4) * 4 + r;
            if (rl >= rmax) continue;
            int t = tok[oe + rows0 + rl];
            float* yr = y + (size_t)t * DO + o0 + l15;
#pragma unroll
            for (int n = 0; n < 4; ++n)
                unsafeAtomicAdd(yr + n * 16, acc[m][n][r]);
        }
    }
}

// ---------------- host launch ----------------
extern "C" void kernel_launch(void* const* d_in, const int* in_sizes, int n_in,
                              void* d_out, int out_size, void* d_ws, size_t ws_size,
                              hipStream_t stream)
{
    const float* x  = (const float*)d_in[0];
    const float* gw = (const float*)d_in[1];
    const float* wg = (const float*)d_in[2];
    const float* bg = (const float*)d_in[3];
    const float* wu = (const float*)d_in[4];
    const float* bu = (const float*)d_in[5];
    const float* wd = (const float*)d_in[6];
    const float* bd = (const float*)d_in[7];
    float* y = (float*)d_out;
    float* loss = y + (size_t)TN * DO;

    uint8_t* ws = (uint8_t*)d_ws;
    u16*   x16   = (u16*)(ws + 0);             // 33,554,432
    u16*   inter = (u16*)(ws + 33554432ull);   // 23,068,672 (stride DHP; col1376=score)
    u16*   wg16  = (u16*)(ws + 56623104ull);   // 90,177,536
    u16*   wu16  = (u16*)(ws + 146800640ull);  // 90,177,536
    u16*   wd16  = (u16*)(ws + 236978176ull);  // 92,274,688 (stride DHP; col1376=b_down)
    int*   tok   = (int*)(ws + 329252864ull);
    float* sc    = (float*)(ws + 329285632ull);
    int*   tke   = (int*)(ws + 329318400ull);
    float* tks   = (float*)(ws + 329351168ull);
    int*   misc  = (int*)(ws + 329383936ull);
    int* cnt = misc; int* fill = misc + 8; int* off = misc + 16;
    float* imp = (float*)(misc + 24);

    hipMemsetAsync(misc, 0, 128, stream);
    hipMemsetAsync(d_out, 0, (size_t)out_size * 4, stream);
    k_cvt_gate<<<70656, 256, 0, stream>>>(x, gw, wg, wu, wd, bd,
                                          x16, wg16, wu16, wd16,
                                          tke, tks, cnt, imp);
    k_scatter_fin<<<16, 256, 0, stream>>>(tke, tks, cnt, imp, off, fill, tok, sc, loss);
    k_stage1s<<<dim3(256, 22), 128, 0, stream>>>(x16, wg16, wu16, bg, bu, cnt, off, tok, sc, inter);
    k_stage2s<<<dim3(256, 64), 128, 0, stream>>>(inter, wd16, cnt, off, tok, y);
}

// Round 15
// 827.366 us; speedup vs baseline: 1.0463x; 1.0463x over previous
//
#include <hip/hip_runtime.h>
#include <hip/hip_bf16.h>
#include <stdint.h>

#define TN 4096      // tokens (B*S)
#define DI 4096      // input dim
#define DH 1376      // GLU hidden dim
#define DHP 1408     // padded hidden (22*64, 44*32)
#define DO 4096      // output dim
#define NE 8         // experts
#define NPAIR 8192   // TN * K

typedef unsigned short u16;
typedef __bf16 bf16x8 __attribute__((ext_vector_type(8)));
typedef float f32x4 __attribute__((ext_vector_type(4)));
typedef uint32_t u32x4 __attribute__((ext_vector_type(4)));

__device__ __forceinline__ uint32_t pack2bf(float a, float b) {
    union { float f; uint32_t u; } ua, ub;
    ua.f = a; ub.f = b;
    uint32_t lo = (ua.u + 0x7fffu + ((ua.u >> 16) & 1u)) >> 16;
    uint32_t hi = (ub.u + 0x7fffu + ((ub.u >> 16) & 1u)) >> 16;
    return lo | (hi << 16);
}
__device__ __forceinline__ u16 f2bf(float a) {
    union { float f; uint32_t u; } ua; ua.f = a;
    return (u16)((ua.u + 0x7fffu + ((ua.u >> 16) & 1u)) >> 16);
}
__device__ __forceinline__ void gload16(const void* g, void* l) {
    __builtin_amdgcn_global_load_lds(
        (const __attribute__((address_space(1))) void*)g,
        (__attribute__((address_space(3))) void*)l, 16, 0, 0);
}
#define MEMFENCE() asm volatile("" ::: "memory")

// ---------------- fused: weight convert (bulk BW) + gate (compute) ----------------
__global__ __launch_bounds__(256) void k_cvt_gate(
    const float* __restrict__ x, const float* __restrict__ gw,
    const float* __restrict__ wg, const float* __restrict__ wu,
    const float* __restrict__ wd, const float* __restrict__ bd,
    u16* __restrict__ x16, u16* __restrict__ wg16, u16* __restrict__ wu16,
    u16* __restrict__ wd16,
    int* __restrict__ tke, float* __restrict__ tks,
    int* __restrict__ cnt, float* __restrict__ imp)
{
    int tid = threadIdx.x;
    if (blockIdx.x < TN) {
        int t = blockIdx.x;
        const float* xr = x + (size_t)t * DI;
        double acc[NE];
#pragma unroll
        for (int e = 0; e < NE; ++e) acc[e] = 0.0;
#pragma unroll
        for (int j = 0; j < 4; ++j) {
            int i4 = (j * 256 + tid) * 4;
            float4 xv = *(const float4*)(xr + i4);
            uint2 p; p.x = pack2bf(xv.x, xv.y); p.y = pack2bf(xv.z, xv.w);
            *(uint2*)(x16 + (size_t)t * DI + i4) = p;
#pragma unroll
            for (int e = 0; e < NE; ++e) {
                float4 wv = *(const float4*)(gw + (size_t)e * DI + i4);
                acc[e] = fma((double)xv.x, (double)wv.x, acc[e]);
                acc[e] = fma((double)xv.y, (double)wv.y, acc[e]);
                acc[e] = fma((double)xv.z, (double)wv.z, acc[e]);
                acc[e] = fma((double)xv.w, (double)wv.w, acc[e]);
            }
        }
#pragma unroll
        for (int o = 32; o > 0; o >>= 1)
#pragma unroll
            for (int e = 0; e < NE; ++e) acc[e] += __shfl_down(acc[e], o, 64);
        __shared__ double lred[4][NE];
        if ((tid & 63) == 0)
#pragma unroll
            for (int e = 0; e < NE; ++e) lred[tid >> 6][e] = acc[e];
        __syncthreads();
        if (tid == 0) {
            double lg[NE];
#pragma unroll
            for (int e = 0; e < NE; ++e) lg[e] = lred[0][e] + lred[1][e] + lred[2][e] + lred[3][e];
            int e1 = 0;
            for (int e = 1; e < NE; ++e) if (lg[e] > lg[e1]) e1 = e;
            int e2 = -1;
            for (int e = 0; e < NE; ++e) { if (e == e1) continue; if (e2 < 0 || lg[e] > lg[e2]) e2 = e; }
            float d = (float)(lg[e2] - lg[e1]);
            float ed = expf(d);
            float s1 = 1.0f / (1.0f + ed);
            float s2 = ed / (1.0f + ed);
            tke[2 * t] = e1; tke[2 * t + 1] = e2;
            tks[2 * t] = s1; tks[2 * t + 1] = s2;
            atomicAdd(&cnt[e1], 1); atomicAdd(&cnt[e2], 1);
            unsafeAtomicAdd(&imp[e1], s1); unsafeAtomicAdd(&imp[e2], s2);
        }
        return;
    }
    int i = (blockIdx.x - TN) * 256 + tid;
    if (i < 11272192) {
        const float* src = (i < 5636096) ? wg : wu;
        u16* dst = (i < 5636096) ? wg16 : wu16;
        int j = (i < 5636096) ? i : i - 5636096;
        const float4* s = (const float4*)(src + (size_t)j * 8);
        float4 a = s[0], b = s[1];
        u32x4 v = {pack2bf(a.x, a.y), pack2bf(a.z, a.w), pack2bf(b.x, b.y), pack2bf(b.z, b.w)};
        *(u32x4*)(dst + (size_t)j * 8) = v;
    } else {
        int j = i - 11272192;
        if (j >= 5767168) return;
        int row = j / 176, c8 = (j % 176) * 8;
        u32x4 v = {0u, 0u, 0u, 0u};
        if (c8 < DH) {
            const float4* s = (const float4*)(wd + (size_t)row * DH + c8);
            float4 a = s[0], b = s[1];
            v = (u32x4){pack2bf(a.x, a.y), pack2bf(a.z, a.w), pack2bf(b.x, b.y), pack2bf(b.z, b.w)};
        } else if (c8 == DH) {
            v.x = (uint32_t)f2bf(bd[row]);   // bias fold: pairs with inter col 1376 = score
        }
        *(u32x4*)(wd16 + (size_t)row * DHP + c8) = v;
    }
}

// ---------------- scatter + finalize (off/loss) ----------------
__global__ __launch_bounds__(256) void k_scatter_fin(
    const int* __restrict__ tke, const float* __restrict__ tks,
    const int* __restrict__ cnt, const float* __restrict__ imp,
    int* __restrict__ off, int* __restrict__ fill,
    int* __restrict__ tok, float* __restrict__ sc, float* __restrict__ loss_out)
{
    int loc[NE]; int o = 0;
#pragma unroll
    for (int e = 0; e < NE; ++e) { loc[e] = o; o += cnt[e]; }
    if (blockIdx.x == 0 && threadIdx.x == 0) {
#pragma unroll
        for (int e = 0; e < NE; ++e) off[e] = loc[e];
        float m1 = 0.f, m2 = 0.f;
        for (int e = 0; e < NE; ++e) { m1 += imp[e]; m2 += (float)cnt[e]; }
        m1 *= 0.125f; m2 *= 0.125f;
        float v1 = 0.f, v2 = 0.f;
        for (int e = 0; e < NE; ++e) {
            float d1 = imp[e] - m1, d2 = (float)cnt[e] - m2;
            v1 += d1 * d1; v2 += d2 * d2;
        }
        v1 /= 7.0f; v2 /= 7.0f;
        *loss_out = 0.01f * (v1 / (m1 * m1 + 1e-10f) + v2 / (m2 * m2 + 1e-10f));
    }
    int t = blockIdx.x * 256 + threadIdx.x;
    if (t >= TN) return;
#pragma unroll
    for (int k = 0; k < 2; ++k) {
        int e = tke[2 * t + k];
        int pos = loc[e] + atomicAdd(&fill[e], 1);
        tok[pos] = t; sc[pos] = tks[2 * t + k];
    }
}

// ============ stage-1: round-7/12 best (3-buffer counted vmcnt, BK=32) ============
__global__ __launch_bounds__(256, 2) void k_stage1g(
    const u16* __restrict__ x16,
    const u16* __restrict__ wg16, const u16* __restrict__ wu16,
    const float* __restrict__ bg, const float* __restrict__ bu,
    const int* __restrict__ cnt, const int* __restrict__ off,
    const int* __restrict__ tok, const float* __restrict__ sc,
    u16* __restrict__ inter)
{
    int e = blockIdx.x & 7;
    int ce = cnt[e];
    int rows0 = (blockIdx.x >> 3) * 128;
    if (rows0 >= ce) return;
    int oe = off[e];
    int h0 = blockIdx.y * 128;
    int tid = threadIdx.x;

    __shared__ u16 As0[128 * 32]; __shared__ u16 As1[128 * 32]; __shared__ u16 As2[128 * 32];
    __shared__ u16 Gs0[128 * 32]; __shared__ u16 Gs1[128 * 32]; __shared__ u16 Gs2[128 * 32];
    __shared__ u16 Us0[128 * 32]; __shared__ u16 Us1[128 * 32]; __shared__ u16 Us2[128 * 32];

    int swz = ((tid & 3) ^ ((tid >> 3) & 3)) * 8;
    const u16* ab0; const u16* ab1; const u16* gb0; const u16* gb1;
    const u16* ub0; const u16* ub1;
    {
        int rl0 = tid >> 2, rl1 = 64 + (tid >> 2);
        int rg0 = oe + min(rows0 + rl0, ce - 1);
        int rg1 = oe + min(rows0 + rl1, ce - 1);
        ab0 = x16 + (size_t)tok[rg0] * DI + swz;
        ab1 = x16 + (size_t)tok[rg1] * DI + swz;
        int hr0 = min(h0 + rl0, DH - 1), hr1 = min(h0 + rl1, DH - 1);
        gb0 = wg16 + ((size_t)e * DH + hr0) * DI + swz;
        gb1 = wg16 + ((size_t)e * DH + hr1) * DI + swz;
        ub0 = wu16 + ((size_t)e * DH + hr0) * DI + swz;
        ub1 = wu16 + ((size_t)e * DH + hr1) * DI + swz;
    }

    int wid = tid >> 6, lane = tid & 63;
    int ldsw = wid * 512;
    int wm = wid >> 1, wn = wid & 1;
    int rA = wm * 64 + (lane & 15);
    int rB = wn * 64 + (lane & 15);
    int colb = (((lane >> 4) ^ ((lane >> 1) & 3)) & 3) * 8;

    f32x4 accg[4][4], accu[4][4];
    f32x4 vz = {0.f, 0.f, 0.f, 0.f};
#pragma unroll
    for (int m = 0; m < 4; ++m)
#pragma unroll
        for (int n = 0; n < 4; ++n) { accg[m][n] = vz; accu[m][n] = vz; }

#define S1_STAGE(A_, G_, U_, K0)                                   \
    do {                                                           \
        gload16(ab0 + (K0), &A_[ldsw]);                            \
        gload16(ab1 + (K0), &A_[2048 + ldsw]);                     \
        gload16(gb0 + (K0), &G_[ldsw]);                            \
        gload16(gb1 + (K0), &G_[2048 + ldsw]);                     \
        gload16(ub0 + (K0), &U_[ldsw]);                            \
        gload16(ub1 + (K0), &U_[2048 + ldsw]);                     \
    } while (0)

#define S1_COMPUTE(A_, G_, U_)                                     \
    do {                                                           \
        bf16x8 a[4], g[4], u[4];                                   \
        _Pragma("unroll")                                          \
        for (int m = 0; m < 4; ++m)                                \
            a[m] = *(const bf16x8*)&A_[(rA + m * 16) * 32 + colb]; \
        _Pragma("unroll")                                          \
        for (int n = 0; n < 4; ++n) {                              \
            g[n] = *(const bf16x8*)&G_[(rB + n * 16) * 32 + colb]; \
            u[n] = *(const bf16x8*)&U_[(rB + n * 16) * 32 + colb]; \
        }                                                          \
        __builtin_amdgcn_s_setprio(1);                             \
        _Pragma("unroll")                                          \
        for (int m = 0; m < 4; ++m)                                \
            _Pragma("unroll")                                      \
            for (int n = 0; n < 4; ++n) {                          \
                accg[m][n] = __builtin_amdgcn_mfma_f32_16x16x32_bf16(a[m], g[n], accg[m][n], 0, 0, 0); \
                accu[m][n] = __builtin_amdgcn_mfma_f32_16x16x32_bf16(a[m], u[n], accu[m][n], 0, 0, 0); \
            }                                                      \
        __builtin_amdgcn_s_setprio(0);                             \
    } while (0)

#define S1_PHASE(A_, G_, U_, KN)                                   \
    do {                                                           \
        asm volatile("s_waitcnt vmcnt(12)" ::: "memory");          \
        __builtin_amdgcn_s_barrier();                              \
        MEMFENCE();                                                \
        S1_COMPUTE(A_, G_, U_);                                    \
        __builtin_amdgcn_s_barrier();                              \
        MEMFENCE();                                                \
        S1_STAGE(A_, G_, U_, KN);                                  \
    } while (0)

    const int NT = DI / 32;        // 128
    const int KL = (NT - 1) * 32;
    S1_STAGE(As0, Gs0, Us0, 0);
    S1_STAGE(As1, Gs1, Us1, 32);
    S1_STAGE(As2, Gs2, Us2, 64);

    for (int kt = 0; kt + 4 < NT; kt += 3) {
        S1_PHASE(As0, Gs0, Us0, min((kt + 3) * 32, KL));
        S1_PHASE(As1, Gs1, Us1, min((kt + 4) * 32, KL));
        S1_PHASE(As2, Gs2, Us2, min((kt + 5) * 32, KL));
    }
    asm volatile("s_waitcnt vmcnt(12)" ::: "memory");
    __builtin_amdgcn_s_barrier();
    MEMFENCE();
    S1_COMPUTE(As0, Gs0, Us0);
    asm volatile("s_waitcnt vmcnt(6)" ::: "memory");
    __builtin_amdgcn_s_barrier();
    MEMFENCE();
    S1_COMPUTE(As1, Gs1, Us1);
    asm volatile("s_waitcnt vmcnt(0)" ::: "memory");
#undef S1_STAGE
#undef S1_COMPUTE
#undef S1_PHASE

    int rmax = ce - rows0;
    float bgv[4], buv[4];
    int hc[4]; bool hok[4];
#pragma unroll
    for (int n = 0; n < 4; ++n) {
        hc[n] = h0 + wn * 64 + n * 16 + (lane & 15);
        hok[n] = hc[n] < DH;
        bgv[n] = hok[n] ? bg[e * DH + hc[n]] : 0.f;
        buv[n] = hok[n] ? bu[e * DH + hc[n]] : 0.f;
    }
#pragma unroll
    for (int m = 0; m < 4; ++m) {
#pragma unroll
        for (int r = 0; r < 4; ++r) {
            int rl = wm * 64 + m * 16 + (lane >> 4) * 4 + r;
            if (rl < rmax) {
                int rg = oe + rows0 + rl;
                float s = sc[rg];
                size_t rowb = (size_t)rg * DHP;
#pragma unroll
                for (int n = 0; n < 4; ++n) {
                    float v = 0.f;
                    if (hok[n]) {
                        float gv = accg[m][n][r] + bgv[n];
                        float uv = accu[m][n][r] + buv[n];
                        float sig = 1.0f / (1.0f + __expf(-gv));
                        v = s * gv * sig * uv;
                    } else if (hc[n] == DH) {
                        v = s;          // bias-fold: pairs with wd16 col 1376
                    }
                    inter[rowb + hc[n]] = f2bf(v);
                }
            }
        }
    }
}

// ============ stage-2: 256x128 tile, BK=32, wave 128x64 (32 MFMA/barrier) ============
// r13 showed BK=64 is not the lever; the untried cell is doubling M at BK=32:
// 32 MFMA per barrier pair via acc[8][4], LDS 48KB (A 2x16KB + B 2x8KB) -> 3
// blocks/CU (r10's 96KB/1-block failure avoided). Same 4-slot swizzle, rule-21,
// wave-uniform dests, r8 counted-vmcnt(6) schedule.
__global__ __launch_bounds__(256, 2) void k_stage2m(
    const u16* __restrict__ inter, const u16* __restrict__ wd16,
    const int* __restrict__ cnt, const int* __restrict__ off,
    const int* __restrict__ tok, float* __restrict__ y)
{
    int e = blockIdx.x & 7;
    int ce = cnt[e];
    int rows0 = (blockIdx.x >> 3) * 256;
    if (rows0 >= ce) return;
    int oe = off[e];
    int o0 = blockIdx.y * 128;
    int tid = threadIdx.x;

    __shared__ u16 As0[256 * 32]; __shared__ u16 As1[256 * 32];   // 16KB each
    __shared__ u16 Bs0[128 * 32]; __shared__ u16 Bs1[128 * 32];   // 8KB each

    int swz = ((tid & 3) ^ ((tid >> 3) & 3)) * 8;
    // A: load j covers rows j*64 + (tid>>2); B: load c covers rows c*64 + (tid>>2)
    const u16* ab[4]; const u16* bb[2];
#pragma unroll
    for (int j = 0; j < 4; ++j) {
        int ar = min(oe + rows0 + j * 64 + (tid >> 2), NPAIR - 1);
        ab[j] = inter + (size_t)ar * DHP + swz;
    }
#pragma unroll
    for (int c = 0; c < 2; ++c)
        bb[c] = wd16 + ((size_t)e * DO + (o0 + c * 64 + (tid >> 2))) * DHP + swz;

    int wid = tid >> 6, lane = tid & 63;
    int ldsw = wid * 512;                // wave-uniform dest base (u16)
    int wm = wid >> 1, wn = wid & 1;     // wave tile 128 rows x 64 cols
    int l15 = lane & 15, q = lane >> 4;
    int colb = (((q) ^ ((lane >> 1) & 3)) & 3) * 8;
    int rA = wm * 128 + l15;
    int rB = wn * 64 + l15;

    f32x4 acc[8][4];
    f32x4 vz = {0.f, 0.f, 0.f, 0.f};
#pragma unroll
    for (int m = 0; m < 8; ++m)
#pragma unroll
        for (int n = 0; n < 4; ++n) acc[m][n] = vz;

#define S2_STAGE(A_, B_, K0)                                       \
    do {                                                           \
        _Pragma("unroll")                                          \
        for (int j = 0; j < 4; ++j)                                \
            gload16(ab[j] + (K0), &A_[j * 2048 + ldsw]);           \
        _Pragma("unroll")                                          \
        for (int c = 0; c < 2; ++c)                                \
            gload16(bb[c] + (K0), &B_[c * 2048 + ldsw]);           \
    } while (0)

#define S2_COMPUTE(A_, B_)                                         \
    do {                                                           \
        bf16x8 a[8], b[4];                                         \
        _Pragma("unroll")                                          \
        for (int m = 0; m < 8; ++m)                                \
            a[m] = *(const bf16x8*)&A_[(rA + m * 16) * 32 + colb]; \
        _Pragma("unroll")                                          \
        for (int n = 0; n < 4; ++n)                                \
            b[n] = *(const bf16x8*)&B_[(rB + n * 16) * 32 + colb]; \
        __builtin_amdgcn_s_setprio(1);                             \
        _Pragma("unroll")                                          \
        for (int m = 0; m < 8; ++m)                                \
            _Pragma("unroll")                                      \
            for (int n = 0; n < 4; ++n)                            \
                acc[m][n] = __builtin_amdgcn_mfma_f32_16x16x32_bf16(a[m], b[n], acc[m][n], 0, 0, 0); \
        __builtin_amdgcn_s_setprio(0);                             \
    } while (0)

    const int NT = DHP / 32;       // 44, even
    S2_STAGE(As0, Bs0, 0);
    S2_STAGE(As1, Bs1, 32);

    for (int kt = 0; kt < NT - 2; kt += 2) {
        asm volatile("s_waitcnt vmcnt(6)" ::: "memory");
        __builtin_amdgcn_s_barrier();
        MEMFENCE();
        S2_COMPUTE(As0, Bs0);
        __builtin_amdgcn_s_barrier();
        MEMFENCE();
        S2_STAGE(As0, Bs0, (kt + 2) * 32);
        asm volatile("s_waitcnt vmcnt(6)" ::: "memory");
        __builtin_amdgcn_s_barrier();
        MEMFENCE();
        S2_COMPUTE(As1, Bs1);
        __builtin_amdgcn_s_barrier();
        MEMFENCE();
        S2_STAGE(As1, Bs1, (kt + 3) * 32);
    }
    asm volatile("s_waitcnt vmcnt(6)" ::: "memory");
    __builtin_amdgcn_s_barrier();
    MEMFENCE();
    S2_COMPUTE(As0, Bs0);
    asm volatile("s_waitcnt vmcnt(0)" ::: "memory");
    __builtin_amdgcn_s_barrier();
    MEMFENCE();
    S2_COMPUTE(As1, Bs1);
#undef S2_STAGE
#undef S2_COMPUTE

    int rmax = ce - rows0;
#pragma unroll
    for (int m = 0; m < 8; ++m) {
#pragma unroll
        for (int r = 0; r < 4; ++r) {
            int rl = wm * 128 + m * 16 + q * 4 + r;
            if (rl >= rmax) continue;
            int t = tok[oe + rows0 + rl];
            float* yr = y + (size_t)t * DO + o0 + wn * 64 + l15;
#pragma unroll
            for (int n = 0; n < 4; ++n)
                unsafeAtomicAdd(yr + n * 16, acc[m][n][r]);
        }
    }
}

// ---------------- host launch ----------------
extern "C" void kernel_launch(void* const* d_in, const int* in_sizes, int n_in,
                              void* d_out, int out_size, void* d_ws, size_t ws_size,
                              hipStream_t stream)
{
    const float* x  = (const float*)d_in[0];
    const float* gw = (const float*)d_in[1];
    const float* wg = (const float*)d_in[2];
    const float* bg = (const float*)d_in[3];
    const float* wu = (const float*)d_in[4];
    const float* bu = (const float*)d_in[5];
    const float* wd = (const float*)d_in[6];
    const float* bd = (const float*)d_in[7];
    float* y = (float*)d_out;
    float* loss = y + (size_t)TN * DO;

    uint8_t* ws = (uint8_t*)d_ws;
    u16*   x16   = (u16*)(ws + 0);             // 33,554,432
    u16*   inter = (u16*)(ws + 33554432ull);   // 23,068,672 (stride DHP; col1376=score)
    u16*   wg16  = (u16*)(ws + 56623104ull);   // 90,177,536
    u16*   wu16  = (u16*)(ws + 146800640ull);  // 90,177,536
    u16*   wd16  = (u16*)(ws + 236978176ull);  // 92,274,688 (stride DHP; col1376=b_down)
    int*   tok   = (int*)(ws + 329252864ull);
    float* sc    = (float*)(ws + 329285632ull);
    int*   tke   = (int*)(ws + 329318400ull);
    float* tks   = (float*)(ws + 329351168ull);
    int*   misc  = (int*)(ws + 329383936ull);
    int* cnt = misc; int* fill = misc + 8; int* off = misc + 16;
    float* imp = (float*)(misc + 24);

    hipMemsetAsync(misc, 0, 128, stream);
    hipMemsetAsync(d_out, 0, (size_t)out_size * 4, stream);
    k_cvt_gate<<<70656, 256, 0, stream>>>(x, gw, wg, wu, wd, bd,
                                          x16, wg16, wu16, wd16,
                                          tke, tks, cnt, imp);
    k_scatter_fin<<<16, 256, 0, stream>>>(tke, tks, cnt, imp, off, fill, tok, sc, loss);
    k_stage1g<<<dim3(256, 11), 256, 0, stream>>>(x16, wg16, wu16, bg, bu, cnt, off, tok, sc, inter);
    k_stage2m<<<dim3(128, 32), 256, 0, stream>>>(inter, wd16, cnt, off, tok, y);
}

// Round 16
// 754.702 us; speedup vs baseline: 1.1471x; 1.0963x over previous
//
#include <hip/hip_runtime.h>
#include <hip/hip_bf16.h>
#include <stdint.h>

#define TN 4096      // tokens (B*S)
#define DI 4096      // input dim
#define DH 1376      // GLU hidden dim
#define DHP 1408     // padded hidden (22*64, 44*32)
#define DO 4096      // output dim
#define NE 8         // experts
#define NPAIR 8192   // TN * K

typedef unsigned short u16;
typedef __bf16 bf16x8 __attribute__((ext_vector_type(8)));
typedef float f32x4 __attribute__((ext_vector_type(4)));
typedef uint32_t u32x4 __attribute__((ext_vector_type(4)));

__device__ __forceinline__ uint32_t pack2bf(float a, float b) {
    union { float f; uint32_t u; } ua, ub;
    ua.f = a; ub.f = b;
    uint32_t lo = (ua.u + 0x7fffu + ((ua.u >> 16) & 1u)) >> 16;
    uint32_t hi = (ub.u + 0x7fffu + ((ub.u >> 16) & 1u)) >> 16;
    return lo | (hi << 16);
}
__device__ __forceinline__ u16 f2bf(float a) {
    union { float f; uint32_t u; } ua; ua.f = a;
    return (u16)((ua.u + 0x7fffu + ((ua.u >> 16) & 1u)) >> 16);
}
__device__ __forceinline__ float bflo(uint32_t u) {
    union { uint32_t u; float f; } v; v.u = u << 16; return v.f;
}
__device__ __forceinline__ float bfhi(uint32_t u) {
    union { uint32_t u; float f; } v; v.u = u & 0xffff0000u; return v.f;
}
__device__ __forceinline__ void gload16(const void* g, void* l) {
    __builtin_amdgcn_global_load_lds(
        (const __attribute__((address_space(1))) void*)g,
        (__attribute__((address_space(3))) void*)l, 16, 0, 0);
}
#define MEMFENCE() asm volatile("" ::: "memory")

// ---------------- fused: weight convert (bulk BW) + gate (compute) ----------------
__global__ __launch_bounds__(256) void k_cvt_gate(
    const float* __restrict__ x, const float* __restrict__ gw,
    const float* __restrict__ wg, const float* __restrict__ wu,
    const float* __restrict__ wd, const float* __restrict__ bd,
    u16* __restrict__ x16, u16* __restrict__ wg16, u16* __restrict__ wu16,
    u16* __restrict__ wd16,
    int* __restrict__ tke, float* __restrict__ tks,
    int* __restrict__ cnt, float* __restrict__ imp)
{
    int tid = threadIdx.x;
    if (blockIdx.x < TN) {
        int t = blockIdx.x;
        const float* xr = x + (size_t)t * DI;
        double acc[NE];
#pragma unroll
        for (int e = 0; e < NE; ++e) acc[e] = 0.0;
#pragma unroll
        for (int j = 0; j < 4; ++j) {
            int i4 = (j * 256 + tid) * 4;
            float4 xv = *(const float4*)(xr + i4);
            uint2 p; p.x = pack2bf(xv.x, xv.y); p.y = pack2bf(xv.z, xv.w);
            *(uint2*)(x16 + (size_t)t * DI + i4) = p;
#pragma unroll
            for (int e = 0; e < NE; ++e) {
                float4 wv = *(const float4*)(gw + (size_t)e * DI + i4);
                acc[e] = fma((double)xv.x, (double)wv.x, acc[e]);
                acc[e] = fma((double)xv.y, (double)wv.y, acc[e]);
                acc[e] = fma((double)xv.z, (double)wv.z, acc[e]);
                acc[e] = fma((double)xv.w, (double)wv.w, acc[e]);
            }
        }
#pragma unroll
        for (int o = 32; o > 0; o >>= 1)
#pragma unroll
            for (int e = 0; e < NE; ++e) acc[e] += __shfl_down(acc[e], o, 64);
        __shared__ double lred[4][NE];
        if ((tid & 63) == 0)
#pragma unroll
            for (int e = 0; e < NE; ++e) lred[tid >> 6][e] = acc[e];
        __syncthreads();
        if (tid == 0) {
            double lg[NE];
#pragma unroll
            for (int e = 0; e < NE; ++e) lg[e] = lred[0][e] + lred[1][e] + lred[2][e] + lred[3][e];
            int e1 = 0;
            for (int e = 1; e < NE; ++e) if (lg[e] > lg[e1]) e1 = e;
            int e2 = -1;
            for (int e = 0; e < NE; ++e) { if (e == e1) continue; if (e2 < 0 || lg[e] > lg[e2]) e2 = e; }
            float d = (float)(lg[e2] - lg[e1]);
            float ed = expf(d);
            float s1 = 1.0f / (1.0f + ed);
            float s2 = ed / (1.0f + ed);
            tke[2 * t] = e1; tke[2 * t + 1] = e2;
            tks[2 * t] = s1; tks[2 * t + 1] = s2;
            atomicAdd(&cnt[e1], 1); atomicAdd(&cnt[e2], 1);
            unsafeAtomicAdd(&imp[e1], s1); unsafeAtomicAdd(&imp[e2], s2);
        }
        return;
    }
    int i = (blockIdx.x - TN) * 256 + tid;
    if (i < 11272192) {
        const float* src = (i < 5636096) ? wg : wu;
        u16* dst = (i < 5636096) ? wg16 : wu16;
        int j = (i < 5636096) ? i : i - 5636096;
        const float4* s = (const float4*)(src + (size_t)j * 8);
        float4 a = s[0], b = s[1];
        u32x4 v = {pack2bf(a.x, a.y), pack2bf(a.z, a.w), pack2bf(b.x, b.y), pack2bf(b.z, b.w)};
        *(u32x4*)(dst + (size_t)j * 8) = v;
    } else {
        int j = i - 11272192;
        if (j >= 5767168) return;
        int row = j / 176, c8 = (j % 176) * 8;
        u32x4 v = {0u, 0u, 0u, 0u};
        if (c8 < DH) {
            const float4* s = (const float4*)(wd + (size_t)row * DH + c8);
            float4 a = s[0], b = s[1];
            v = (u32x4){pack2bf(a.x, a.y), pack2bf(a.z, a.w), pack2bf(b.x, b.y), pack2bf(b.z, b.w)};
        } else if (c8 == DH) {
            v.x = (uint32_t)f2bf(bd[row]);   // bias fold: pairs with inter col 1376 = score
        }
        *(u32x4*)(wd16 + (size_t)row * DHP + c8) = v;
    }
}

// ---------------- scatter + finalize; records pair positions into tke ----------------
__global__ __launch_bounds__(256) void k_scatter_fin(
    int* __restrict__ tke /* in: expert ids; out: pair positions */,
    const float* __restrict__ tks,
    const int* __restrict__ cnt, const float* __restrict__ imp,
    int* __restrict__ off, int* __restrict__ fill,
    int* __restrict__ tok, float* __restrict__ sc, float* __restrict__ loss_out)
{
    int loc[NE]; int o = 0;
#pragma unroll
    for (int e = 0; e < NE; ++e) { loc[e] = o; o += cnt[e]; }
    if (blockIdx.x == 0 && threadIdx.x == 0) {
#pragma unroll
        for (int e = 0; e < NE; ++e) off[e] = loc[e];
        float m1 = 0.f, m2 = 0.f;
        for (int e = 0; e < NE; ++e) { m1 += imp[e]; m2 += (float)cnt[e]; }
        m1 *= 0.125f; m2 *= 0.125f;
        float v1 = 0.f, v2 = 0.f;
        for (int e = 0; e < NE; ++e) {
            float d1 = imp[e] - m1, d2 = (float)cnt[e] - m2;
            v1 += d1 * d1; v2 += d2 * d2;
        }
        v1 /= 7.0f; v2 /= 7.0f;
        *loss_out = 0.01f * (v1 / (m1 * m1 + 1e-10f) + v2 / (m2 * m2 + 1e-10f));
    }
    int t = blockIdx.x * 256 + threadIdx.x;
    if (t >= TN) return;
    int e0 = tke[2 * t], e1 = tke[2 * t + 1];
    float s0 = tks[2 * t], s1 = tks[2 * t + 1];
    int p0 = loc[e0] + atomicAdd(&fill[e0], 1);
    tok[p0] = t; sc[p0] = s0; tke[2 * t] = p0;       // tke now = tpos
    int p1 = loc[e1] + atomicAdd(&fill[e1], 1);
    tok[p1] = t; sc[p1] = s1; tke[2 * t + 1] = p1;
}

// ============ stage-1: round-7/12 best (3-buffer counted vmcnt, BK=32) ============
__global__ __launch_bounds__(256, 2) void k_stage1g(
    const u16* __restrict__ x16,
    const u16* __restrict__ wg16, const u16* __restrict__ wu16,
    const float* __restrict__ bg, const float* __restrict__ bu,
    const int* __restrict__ cnt, const int* __restrict__ off,
    const int* __restrict__ tok, const float* __restrict__ sc,
    u16* __restrict__ inter)
{
    int e = blockIdx.x & 7;
    int ce = cnt[e];
    int rows0 = (blockIdx.x >> 3) * 128;
    if (rows0 >= ce) return;
    int oe = off[e];
    int h0 = blockIdx.y * 128;
    int tid = threadIdx.x;

    __shared__ u16 As0[128 * 32]; __shared__ u16 As1[128 * 32]; __shared__ u16 As2[128 * 32];
    __shared__ u16 Gs0[128 * 32]; __shared__ u16 Gs1[128 * 32]; __shared__ u16 Gs2[128 * 32];
    __shared__ u16 Us0[128 * 32]; __shared__ u16 Us1[128 * 32]; __shared__ u16 Us2[128 * 32];

    int swz = ((tid & 3) ^ ((tid >> 3) & 3)) * 8;
    const u16* ab0; const u16* ab1; const u16* gb0; const u16* gb1;
    const u16* ub0; const u16* ub1;
    {
        int rl0 = tid >> 2, rl1 = 64 + (tid >> 2);
        int rg0 = oe + min(rows0 + rl0, ce - 1);
        int rg1 = oe + min(rows0 + rl1, ce - 1);
        ab0 = x16 + (size_t)tok[rg0] * DI + swz;
        ab1 = x16 + (size_t)tok[rg1] * DI + swz;
        int hr0 = min(h0 + rl0, DH - 1), hr1 = min(h0 + rl1, DH - 1);
        gb0 = wg16 + ((size_t)e * DH + hr0) * DI + swz;
        gb1 = wg16 + ((size_t)e * DH + hr1) * DI + swz;
        ub0 = wu16 + ((size_t)e * DH + hr0) * DI + swz;
        ub1 = wu16 + ((size_t)e * DH + hr1) * DI + swz;
    }

    int wid = tid >> 6, lane = tid & 63;
    int ldsw = wid * 512;
    int wm = wid >> 1, wn = wid & 1;
    int rA = wm * 64 + (lane & 15);
    int rB = wn * 64 + (lane & 15);
    int colb = (((lane >> 4) ^ ((lane >> 1) & 3)) & 3) * 8;

    f32x4 accg[4][4], accu[4][4];
    f32x4 vz = {0.f, 0.f, 0.f, 0.f};
#pragma unroll
    for (int m = 0; m < 4; ++m)
#pragma unroll
        for (int n = 0; n < 4; ++n) { accg[m][n] = vz; accu[m][n] = vz; }

#define S1_STAGE(A_, G_, U_, K0)                                   \
    do {                                                           \
        gload16(ab0 + (K0), &A_[ldsw]);                            \
        gload16(ab1 + (K0), &A_[2048 + ldsw]);                     \
        gload16(gb0 + (K0), &G_[ldsw]);                            \
        gload16(gb1 + (K0), &G_[2048 + ldsw]);                     \
        gload16(ub0 + (K0), &U_[ldsw]);                            \
        gload16(ub1 + (K0), &U_[2048 + ldsw]);                     \
    } while (0)

#define S1_COMPUTE(A_, G_, U_)                                     \
    do {                                                           \
        bf16x8 a[4], g[4], u[4];                                   \
        _Pragma("unroll")                                          \
        for (int m = 0; m < 4; ++m)                                \
            a[m] = *(const bf16x8*)&A_[(rA + m * 16) * 32 + colb]; \
        _Pragma("unroll")                                          \
        for (int n = 0; n < 4; ++n) {                              \
            g[n] = *(const bf16x8*)&G_[(rB + n * 16) * 32 + colb]; \
            u[n] = *(const bf16x8*)&U_[(rB + n * 16) * 32 + colb]; \
        }                                                          \
        __builtin_amdgcn_s_setprio(1);                             \
        _Pragma("unroll")                                          \
        for (int m = 0; m < 4; ++m)                                \
            _Pragma("unroll")                                      \
            for (int n = 0; n < 4; ++n) {                          \
                accg[m][n] = __builtin_amdgcn_mfma_f32_16x16x32_bf16(a[m], g[n], accg[m][n], 0, 0, 0); \
                accu[m][n] = __builtin_amdgcn_mfma_f32_16x16x32_bf16(a[m], u[n], accu[m][n], 0, 0, 0); \
            }                                                      \
        __builtin_amdgcn_s_setprio(0);                             \
    } while (0)

#define S1_PHASE(A_, G_, U_, KN)                                   \
    do {                                                           \
        asm volatile("s_waitcnt vmcnt(12)" ::: "memory");          \
        __builtin_amdgcn_s_barrier();                              \
        MEMFENCE();                                                \
        S1_COMPUTE(A_, G_, U_);                                    \
        __builtin_amdgcn_s_barrier();                              \
        MEMFENCE();                                                \
        S1_STAGE(A_, G_, U_, KN);                                  \
    } while (0)

    const int NT = DI / 32;        // 128
    const int KL = (NT - 1) * 32;
    S1_STAGE(As0, Gs0, Us0, 0);
    S1_STAGE(As1, Gs1, Us1, 32);
    S1_STAGE(As2, Gs2, Us2, 64);

    for (int kt = 0; kt + 4 < NT; kt += 3) {
        S1_PHASE(As0, Gs0, Us0, min((kt + 3) * 32, KL));
        S1_PHASE(As1, Gs1, Us1, min((kt + 4) * 32, KL));
        S1_PHASE(As2, Gs2, Us2, min((kt + 5) * 32, KL));
    }
    asm volatile("s_waitcnt vmcnt(12)" ::: "memory");
    __builtin_amdgcn_s_barrier();
    MEMFENCE();
    S1_COMPUTE(As0, Gs0, Us0);
    asm volatile("s_waitcnt vmcnt(6)" ::: "memory");
    __builtin_amdgcn_s_barrier();
    MEMFENCE();
    S1_COMPUTE(As1, Gs1, Us1);
    asm volatile("s_waitcnt vmcnt(0)" ::: "memory");
#undef S1_STAGE
#undef S1_COMPUTE
#undef S1_PHASE

    int rmax = ce - rows0;
    float bgv[4], buv[4];
    int hc[4]; bool hok[4];
#pragma unroll
    for (int n = 0; n < 4; ++n) {
        hc[n] = h0 + wn * 64 + n * 16 + (lane & 15);
        hok[n] = hc[n] < DH;
        bgv[n] = hok[n] ? bg[e * DH + hc[n]] : 0.f;
        buv[n] = hok[n] ? bu[e * DH + hc[n]] : 0.f;
    }
#pragma unroll
    for (int m = 0; m < 4; ++m) {
#pragma unroll
        for (int r = 0; r < 4; ++r) {
            int rl = wm * 64 + m * 16 + (lane >> 4) * 4 + r;
            if (rl < rmax) {
                int rg = oe + rows0 + rl;
                float s = sc[rg];
                size_t rowb = (size_t)rg * DHP;
#pragma unroll
                for (int n = 0; n < 4; ++n) {
                    float v = 0.f;
                    if (hok[n]) {
                        float gv = accg[m][n][r] + bgv[n];
                        float uv = accu[m][n][r] + buv[n];
                        float sig = 1.0f / (1.0f + __expf(-gv));
                        v = s * gv * sig * uv;
                    } else if (hc[n] == DH) {
                        v = s;          // bias-fold: pairs with wd16 col 1376
                    }
                    inter[rowb + hc[n]] = f2bf(v);
                }
            }
        }
    }
}

// ============ stage-2: r12 schedule, ATOMIC-FREE pair-partial output ============
// Writes bf16 partials to ypart[NPAIR][DO] (plain stores, disjoint rows/cols
// per block) instead of 33.5M f32 atomicAdds into y. ypart aliases the dead
// wg16 region (stage1 complete). k_reduce sums the two partials per token.
__global__ __launch_bounds__(256, 2) void k_stage2p(
    const u16* __restrict__ inter, const u16* __restrict__ wd16,
    const int* __restrict__ cnt, const int* __restrict__ off,
    u16* __restrict__ ypart)
{
    int e = blockIdx.x & 7;
    int ce = cnt[e];
    int rows0 = (blockIdx.x >> 3) * 128;
    if (rows0 >= ce) return;
    int oe = off[e];
    int o0 = blockIdx.y * 128;
    int tid = threadIdx.x;

    __shared__ u16 As0[128 * 32]; __shared__ u16 As1[128 * 32];
    __shared__ u16 Bs0[128 * 32]; __shared__ u16 Bs1[128 * 32];

    int swz = ((tid & 3) ^ ((tid >> 3) & 3)) * 8;
    const u16* ab0; const u16* ab1; const u16* bb0; const u16* bb1;
    {
        int rl0 = tid >> 2, rl1 = 64 + (tid >> 2);
        int ar0 = min(oe + rows0 + rl0, NPAIR - 1);
        int ar1 = min(oe + rows0 + rl1, NPAIR - 1);
        ab0 = inter + (size_t)ar0 * DHP + swz;
        ab1 = inter + (size_t)ar1 * DHP + swz;
        bb0 = wd16 + ((size_t)e * DO + (o0 + rl0)) * DHP + swz;
        bb1 = wd16 + ((size_t)e * DO + (o0 + rl1)) * DHP + swz;
    }

    int wid = tid >> 6, lane = tid & 63;
    int ldsw = wid * 512;
    int wm = wid >> 1, wn = wid & 1;
    int rA = wm * 64 + (lane & 15);
    int rB = wn * 64 + (lane & 15);
    int colb = (((lane >> 4) ^ ((lane >> 1) & 3)) & 3) * 8;

    f32x4 acc[4][4];
    f32x4 vz = {0.f, 0.f, 0.f, 0.f};
#pragma unroll
    for (int m = 0; m < 4; ++m)
#pragma unroll
        for (int n = 0; n < 4; ++n) acc[m][n] = vz;

#define S2_STAGE(A_, B_, K0)                                       \
    do {                                                           \
        gload16(ab0 + (K0), &A_[ldsw]);                            \
        gload16(ab1 + (K0), &A_[2048 + ldsw]);                     \
        gload16(bb0 + (K0), &B_[ldsw]);                            \
        gload16(bb1 + (K0), &B_[2048 + ldsw]);                     \
    } while (0)

#define S2_COMPUTE(A_, B_)                                         \
    do {                                                           \
        bf16x8 a[4], b[4];                                         \
        _Pragma("unroll")                                          \
        for (int m = 0; m < 4; ++m)                                \
            a[m] = *(const bf16x8*)&A_[(rA + m * 16) * 32 + colb]; \
        _Pragma("unroll")                                          \
        for (int n = 0; n < 4; ++n)                                \
            b[n] = *(const bf16x8*)&B_[(rB + n * 16) * 32 + colb]; \
        __builtin_amdgcn_s_setprio(1);                             \
        _Pragma("unroll")                                          \
        for (int m = 0; m < 4; ++m)                                \
            _Pragma("unroll")                                      \
            for (int n = 0; n < 4; ++n)                            \
                acc[m][n] = __builtin_amdgcn_mfma_f32_16x16x32_bf16(a[m], b[n], acc[m][n], 0, 0, 0); \
        __builtin_amdgcn_s_setprio(0);                             \
    } while (0)

    const int NT = DHP / 32;       // 44, even
    S2_STAGE(As0, Bs0, 0);
    S2_STAGE(As1, Bs1, 32);

    for (int kt = 0; kt < NT - 2; kt += 2) {
        asm volatile("s_waitcnt vmcnt(4)" ::: "memory");
        __builtin_amdgcn_s_barrier();
        MEMFENCE();
        S2_COMPUTE(As0, Bs0);
        __builtin_amdgcn_s_barrier();
        MEMFENCE();
        S2_STAGE(As0, Bs0, (kt + 2) * 32);
        asm volatile("s_waitcnt vmcnt(4)" ::: "memory");
        __builtin_amdgcn_s_barrier();
        MEMFENCE();
        S2_COMPUTE(As1, Bs1);
        __builtin_amdgcn_s_barrier();
        MEMFENCE();
        S2_STAGE(As1, Bs1, (kt + 3) * 32);
    }
    asm volatile("s_waitcnt vmcnt(4)" ::: "memory");
    __builtin_amdgcn_s_barrier();
    MEMFENCE();
    S2_COMPUTE(As0, Bs0);
    asm volatile("s_waitcnt vmcnt(0)" ::: "memory");
    __builtin_amdgcn_s_barrier();
    MEMFENCE();
    S2_COMPUTE(As1, Bs1);
#undef S2_STAGE
#undef S2_COMPUTE

    int rmax = ce - rows0;
#pragma unroll
    for (int m = 0; m < 4; ++m) {
#pragma unroll
        for (int r = 0; r < 4; ++r) {
            int rl = wm * 64 + m * 16 + (lane >> 4) * 4 + r;
            if (rl >= rmax) continue;
            size_t rowb = (size_t)(oe + rows0 + rl) * DO + o0 + wn * 64 + (lane & 15);
#pragma unroll
            for (int n = 0; n < 4; ++n)
                ypart[rowb + n * 16] = f2bf(acc[m][n][r]);
        }
    }
}

// ---------------- reduce: y[t] = ypart[p0] + ypart[p1] ----------------
__global__ __launch_bounds__(256) void k_reduce(
    const u16* __restrict__ ypart, const int* __restrict__ tpos,
    float* __restrict__ y)
{
    int t = blockIdx.x, tid = threadIdx.x;
    int p0 = tpos[2 * t], p1 = tpos[2 * t + 1];
    int c = tid * 16;
    const u16* r0 = ypart + (size_t)p0 * DO + c;
    const u16* r1 = ypart + (size_t)p1 * DO + c;
    float* yr = y + (size_t)t * DO + c;
    u32x4 a0 = *(const u32x4*)r0, a1 = *(const u32x4*)(r0 + 8);
    u32x4 b0 = *(const u32x4*)r1, b1 = *(const u32x4*)(r1 + 8);
    uint32_t ua[8] = {a0.x, a0.y, a0.z, a0.w, a1.x, a1.y, a1.z, a1.w};
    uint32_t ub[8] = {b0.x, b0.y, b0.z, b0.w, b1.x, b1.y, b1.z, b1.w};
#pragma unroll
    for (int j = 0; j < 8; ++j) {
        yr[2 * j]     = bflo(ua[j]) + bflo(ub[j]);
        yr[2 * j + 1] = bfhi(ua[j]) + bfhi(ub[j]);
    }
}

// ---------------- host launch ----------------
extern "C" void kernel_launch(void* const* d_in, const int* in_sizes, int n_in,
                              void* d_out, int out_size, void* d_ws, size_t ws_size,
                              hipStream_t stream)
{
    const float* x  = (const float*)d_in[0];
    const float* gw = (const float*)d_in[1];
    const float* wg = (const float*)d_in[2];
    const float* bg = (const float*)d_in[3];
    const float* wu = (const float*)d_in[4];
    const float* bu = (const float*)d_in[5];
    const float* wd = (const float*)d_in[6];
    const float* bd = (const float*)d_in[7];
    float* y = (float*)d_out;
    float* loss = y + (size_t)TN * DO;

    uint8_t* ws = (uint8_t*)d_ws;
    u16*   x16   = (u16*)(ws + 0);             // 33,554,432
    u16*   inter = (u16*)(ws + 33554432ull);   // 23,068,672 (stride DHP; col1376=score)
    u16*   wg16  = (u16*)(ws + 56623104ull);   // 90,177,536 (reused as ypart after stage1)
    u16*   wu16  = (u16*)(ws + 146800640ull);  // 90,177,536
    u16*   wd16  = (u16*)(ws + 236978176ull);  // 92,274,688 (stride DHP; col1376=b_down)
    int*   tok   = (int*)(ws + 329252864ull);
    float* sc    = (float*)(ws + 329285632ull);
    int*   tke   = (int*)(ws + 329318400ull);  // expert ids, then pair positions
    float* tks   = (float*)(ws + 329351168ull);
    int*   misc  = (int*)(ws + 329383936ull);
    int* cnt = misc; int* fill = misc + 8; int* off = misc + 16;
    float* imp = (float*)(misc + 24);
    u16* ypart = wg16;                          // 67,108,864 B needed; wg16 is 90 MB

    hipMemsetAsync(misc, 0, 128, stream);
    k_cvt_gate<<<70656, 256, 0, stream>>>(x, gw, wg, wu, wd, bd,
                                          x16, wg16, wu16, wd16,
                                          tke, tks, cnt, imp);
    k_scatter_fin<<<16, 256, 0, stream>>>(tke, tks, cnt, imp, off, fill, tok, sc, loss);
    k_stage1g<<<dim3(256, 11), 256, 0, stream>>>(x16, wg16, wu16, bg, bu, cnt, off, tok, sc, inter);
    k_stage2p<<<dim3(256, 32), 256, 0, stream>>>(inter, wd16, cnt, off, ypart);
    k_reduce<<<TN, 256, 0, stream>>>(ypart, tke, y);
}

// Round 17
// 752.187 us; speedup vs baseline: 1.1509x; 1.0033x over previous
//
#include <hip/hip_runtime.h>
#include <hip/hip_bf16.h>
#include <stdint.h>

#define TN 4096      // tokens (B*S)
#define DI 4096      // input dim
#define DH 1376      // GLU hidden dim
#define DHP 1408     // padded hidden (22*64, 44*32)
#define DO 4096      // output dim
#define NE 8         // experts
#define NPAIR 8192   // TN * K

typedef unsigned short u16;
typedef __bf16 bf16x8 __attribute__((ext_vector_type(8)));
typedef float f32x4 __attribute__((ext_vector_type(4)));
typedef uint32_t u32x4 __attribute__((ext_vector_type(4)));

__device__ __forceinline__ uint32_t pack2bf(float a, float b) {
    union { float f; uint32_t u; } ua, ub;
    ua.f = a; ub.f = b;
    uint32_t lo = (ua.u + 0x7fffu + ((ua.u >> 16) & 1u)) >> 16;
    uint32_t hi = (ub.u + 0x7fffu + ((ub.u >> 16) & 1u)) >> 16;
    return lo | (hi << 16);
}
__device__ __forceinline__ u16 f2bf(float a) {
    union { float f; uint32_t u; } ua; ua.f = a;
    return (u16)((ua.u + 0x7fffu + ((ua.u >> 16) & 1u)) >> 16);
}
__device__ __forceinline__ float bflo(uint32_t u) {
    union { uint32_t u; float f; } v; v.u = u << 16; return v.f;
}
__device__ __forceinline__ float bfhi(uint32_t u) {
    union { uint32_t u; float f; } v; v.u = u & 0xffff0000u; return v.f;
}
__device__ __forceinline__ void gload16(const void* g, void* l) {
    __builtin_amdgcn_global_load_lds(
        (const __attribute__((address_space(1))) void*)g,
        (__attribute__((address_space(3))) void*)l, 16, 0, 0);
}
#define MEMFENCE() asm volatile("" ::: "memory")

// ---------------- fused: weight convert (bulk BW) + gate (compute) ----------------
__global__ __launch_bounds__(256) void k_cvt_gate(
    const float* __restrict__ x, const float* __restrict__ gw,
    const float* __restrict__ wg, const float* __restrict__ wu,
    const float* __restrict__ wd, const float* __restrict__ bd,
    u16* __restrict__ x16, u16* __restrict__ wg16, u16* __restrict__ wu16,
    u16* __restrict__ wd16,
    int* __restrict__ tke, float* __restrict__ tks,
    int* __restrict__ cnt, float* __restrict__ imp)
{
    int tid = threadIdx.x;
    if (blockIdx.x < TN) {
        int t = blockIdx.x;
        const float* xr = x + (size_t)t * DI;
        double acc[NE];
#pragma unroll
        for (int e = 0; e < NE; ++e) acc[e] = 0.0;
#pragma unroll
        for (int j = 0; j < 4; ++j) {
            int i4 = (j * 256 + tid) * 4;
            float4 xv = *(const float4*)(xr + i4);
            uint2 p; p.x = pack2bf(xv.x, xv.y); p.y = pack2bf(xv.z, xv.w);
            *(uint2*)(x16 + (size_t)t * DI + i4) = p;
#pragma unroll
            for (int e = 0; e < NE; ++e) {
                float4 wv = *(const float4*)(gw + (size_t)e * DI + i4);
                acc[e] = fma((double)xv.x, (double)wv.x, acc[e]);
                acc[e] = fma((double)xv.y, (double)wv.y, acc[e]);
                acc[e] = fma((double)xv.z, (double)wv.z, acc[e]);
                acc[e] = fma((double)xv.w, (double)wv.w, acc[e]);
            }
        }
#pragma unroll
        for (int o = 32; o > 0; o >>= 1)
#pragma unroll
            for (int e = 0; e < NE; ++e) acc[e] += __shfl_down(acc[e], o, 64);
        __shared__ double lred[4][NE];
        if ((tid & 63) == 0)
#pragma unroll
            for (int e = 0; e < NE; ++e) lred[tid >> 6][e] = acc[e];
        __syncthreads();
        if (tid == 0) {
            double lg[NE];
#pragma unroll
            for (int e = 0; e < NE; ++e) lg[e] = lred[0][e] + lred[1][e] + lred[2][e] + lred[3][e];
            int e1 = 0;
            for (int e = 1; e < NE; ++e) if (lg[e] > lg[e1]) e1 = e;
            int e2 = -1;
            for (int e = 0; e < NE; ++e) { if (e == e1) continue; if (e2 < 0 || lg[e] > lg[e2]) e2 = e; }
            float d = (float)(lg[e2] - lg[e1]);
            float ed = expf(d);
            float s1 = 1.0f / (1.0f + ed);
            float s2 = ed / (1.0f + ed);
            tke[2 * t] = e1; tke[2 * t + 1] = e2;
            tks[2 * t] = s1; tks[2 * t + 1] = s2;
            atomicAdd(&cnt[e1], 1); atomicAdd(&cnt[e2], 1);
            unsafeAtomicAdd(&imp[e1], s1); unsafeAtomicAdd(&imp[e2], s2);
        }
        return;
    }
    int i = (blockIdx.x - TN) * 256 + tid;
    if (i < 11272192) {
        const float* src = (i < 5636096) ? wg : wu;
        u16* dst = (i < 5636096) ? wg16 : wu16;
        int j = (i < 5636096) ? i : i - 5636096;
        const float4* s = (const float4*)(src + (size_t)j * 8);
        float4 a = s[0], b = s[1];
        u32x4 v = {pack2bf(a.x, a.y), pack2bf(a.z, a.w), pack2bf(b.x, b.y), pack2bf(b.z, b.w)};
        *(u32x4*)(dst + (size_t)j * 8) = v;
    } else {
        int j = i - 11272192;
        if (j >= 5767168) return;
        int row = j / 176, c8 = (j % 176) * 8;
        u32x4 v = {0u, 0u, 0u, 0u};
        if (c8 < DH) {
            const float4* s = (const float4*)(wd + (size_t)row * DH + c8);
            float4 a = s[0], b = s[1];
            v = (u32x4){pack2bf(a.x, a.y), pack2bf(a.z, a.w), pack2bf(b.x, b.y), pack2bf(b.z, b.w)};
        } else if (c8 == DH) {
            v.x = (uint32_t)f2bf(bd[row]);   // bias fold: pairs with inter col 1376 = score
        }
        *(u32x4*)(wd16 + (size_t)row * DHP + c8) = v;
    }
}

// ---------------- scatter + finalize; records pair positions into tke ----------------
__global__ __launch_bounds__(256) void k_scatter_fin(
    int* __restrict__ tke /* in: expert ids; out: pair positions */,
    const float* __restrict__ tks,
    const int* __restrict__ cnt, const float* __restrict__ imp,
    int* __restrict__ off, int* __restrict__ fill,
    int* __restrict__ tok, float* __restrict__ sc, float* __restrict__ loss_out)
{
    int loc[NE]; int o = 0;
#pragma unroll
    for (int e = 0; e < NE; ++e) { loc[e] = o; o += cnt[e]; }
    if (blockIdx.x == 0 && threadIdx.x == 0) {
#pragma unroll
        for (int e = 0; e < NE; ++e) off[e] = loc[e];
        float m1 = 0.f, m2 = 0.f;
        for (int e = 0; e < NE; ++e) { m1 += imp[e]; m2 += (float)cnt[e]; }
        m1 *= 0.125f; m2 *= 0.125f;
        float v1 = 0.f, v2 = 0.f;
        for (int e = 0; e < NE; ++e) {
            float d1 = imp[e] - m1, d2 = (float)cnt[e] - m2;
            v1 += d1 * d1; v2 += d2 * d2;
        }
        v1 /= 7.0f; v2 /= 7.0f;
        *loss_out = 0.01f * (v1 / (m1 * m1 + 1e-10f) + v2 / (m2 * m2 + 1e-10f));
    }
    int t = blockIdx.x * 256 + threadIdx.x;
    if (t >= TN) return;
    int e0 = tke[2 * t], e1 = tke[2 * t + 1];
    float s0 = tks[2 * t], s1 = tks[2 * t + 1];
    int p0 = loc[e0] + atomicAdd(&fill[e0], 1);
    tok[p0] = t; sc[p0] = s0; tke[2 * t] = p0;       // tke now = tpos
    int p1 = loc[e1] + atomicAdd(&fill[e1], 1);
    tok[p1] = t; sc[p1] = s1; tke[2 * t + 1] = p1;
}

// ============ stage-1: 3-buffer counted vmcnt, BK=32; setprio REMOVED ============
// (T5 catalog: setprio on non-8-phase lockstep GEMM is null-to-negative, m190 —
// it delays the staging waves the next phase depends on.)
__global__ __launch_bounds__(256, 2) void k_stage1g(
    const u16* __restrict__ x16,
    const u16* __restrict__ wg16, const u16* __restrict__ wu16,
    const float* __restrict__ bg, const float* __restrict__ bu,
    const int* __restrict__ cnt, const int* __restrict__ off,
    const int* __restrict__ tok, const float* __restrict__ sc,
    u16* __restrict__ inter)
{
    int e = blockIdx.x & 7;
    int ce = cnt[e];
    int rows0 = (blockIdx.x >> 3) * 128;
    if (rows0 >= ce) return;
    int oe = off[e];
    int h0 = blockIdx.y * 128;
    int tid = threadIdx.x;

    __shared__ u16 As0[128 * 32]; __shared__ u16 As1[128 * 32]; __shared__ u16 As2[128 * 32];
    __shared__ u16 Gs0[128 * 32]; __shared__ u16 Gs1[128 * 32]; __shared__ u16 Gs2[128 * 32];
    __shared__ u16 Us0[128 * 32]; __shared__ u16 Us1[128 * 32]; __shared__ u16 Us2[128 * 32];

    int swz = ((tid & 3) ^ ((tid >> 3) & 3)) * 8;
    const u16* ab0; const u16* ab1; const u16* gb0; const u16* gb1;
    const u16* ub0; const u16* ub1;
    {
        int rl0 = tid >> 2, rl1 = 64 + (tid >> 2);
        int rg0 = oe + min(rows0 + rl0, ce - 1);
        int rg1 = oe + min(rows0 + rl1, ce - 1);
        ab0 = x16 + (size_t)tok[rg0] * DI + swz;
        ab1 = x16 + (size_t)tok[rg1] * DI + swz;
        int hr0 = min(h0 + rl0, DH - 1), hr1 = min(h0 + rl1, DH - 1);
        gb0 = wg16 + ((size_t)e * DH + hr0) * DI + swz;
        gb1 = wg16 + ((size_t)e * DH + hr1) * DI + swz;
        ub0 = wu16 + ((size_t)e * DH + hr0) * DI + swz;
        ub1 = wu16 + ((size_t)e * DH + hr1) * DI + swz;
    }

    int wid = tid >> 6, lane = tid & 63;
    int ldsw = wid * 512;
    int wm = wid >> 1, wn = wid & 1;
    int rA = wm * 64 + (lane & 15);
    int rB = wn * 64 + (lane & 15);
    int colb = (((lane >> 4) ^ ((lane >> 1) & 3)) & 3) * 8;

    f32x4 accg[4][4], accu[4][4];
    f32x4 vz = {0.f, 0.f, 0.f, 0.f};
#pragma unroll
    for (int m = 0; m < 4; ++m)
#pragma unroll
        for (int n = 0; n < 4; ++n) { accg[m][n] = vz; accu[m][n] = vz; }

#define S1_STAGE(A_, G_, U_, K0)                                   \
    do {                                                           \
        gload16(ab0 + (K0), &A_[ldsw]);                            \
        gload16(ab1 + (K0), &A_[2048 + ldsw]);                     \
        gload16(gb0 + (K0), &G_[ldsw]);                            \
        gload16(gb1 + (K0), &G_[2048 + ldsw]);                     \
        gload16(ub0 + (K0), &U_[ldsw]);                            \
        gload16(ub1 + (K0), &U_[2048 + ldsw]);                     \
    } while (0)

#define S1_COMPUTE(A_, G_, U_)                                     \
    do {                                                           \
        bf16x8 a[4], g[4], u[4];                                   \
        _Pragma("unroll")                                          \
        for (int m = 0; m < 4; ++m)                                \
            a[m] = *(const bf16x8*)&A_[(rA + m * 16) * 32 + colb]; \
        _Pragma("unroll")                                          \
        for (int n = 0; n < 4; ++n) {                              \
            g[n] = *(const bf16x8*)&G_[(rB + n * 16) * 32 + colb]; \
            u[n] = *(const bf16x8*)&U_[(rB + n * 16) * 32 + colb]; \
        }                                                          \
        _Pragma("unroll")                                          \
        for (int m = 0; m < 4; ++m)                                \
            _Pragma("unroll")                                      \
            for (int n = 0; n < 4; ++n) {                          \
                accg[m][n] = __builtin_amdgcn_mfma_f32_16x16x32_bf16(a[m], g[n], accg[m][n], 0, 0, 0); \
                accu[m][n] = __builtin_amdgcn_mfma_f32_16x16x32_bf16(a[m], u[n], accu[m][n], 0, 0, 0); \
            }                                                      \
    } while (0)

#define S1_PHASE(A_, G_, U_, KN)                                   \
    do {                                                           \
        asm volatile("s_waitcnt vmcnt(12)" ::: "memory");          \
        __builtin_amdgcn_s_barrier();                              \
        MEMFENCE();                                                \
        S1_COMPUTE(A_, G_, U_);                                    \
        __builtin_amdgcn_s_barrier();                              \
        MEMFENCE();                                                \
        S1_STAGE(A_, G_, U_, KN);                                  \
    } while (0)

    const int NT = DI / 32;        // 128
    const int KL = (NT - 1) * 32;
    S1_STAGE(As0, Gs0, Us0, 0);
    S1_STAGE(As1, Gs1, Us1, 32);
    S1_STAGE(As2, Gs2, Us2, 64);

    for (int kt = 0; kt + 4 < NT; kt += 3) {
        S1_PHASE(As0, Gs0, Us0, min((kt + 3) * 32, KL));
        S1_PHASE(As1, Gs1, Us1, min((kt + 4) * 32, KL));
        S1_PHASE(As2, Gs2, Us2, min((kt + 5) * 32, KL));
    }
    asm volatile("s_waitcnt vmcnt(12)" ::: "memory");
    __builtin_amdgcn_s_barrier();
    MEMFENCE();
    S1_COMPUTE(As0, Gs0, Us0);
    asm volatile("s_waitcnt vmcnt(6)" ::: "memory");
    __builtin_amdgcn_s_barrier();
    MEMFENCE();
    S1_COMPUTE(As1, Gs1, Us1);
    asm volatile("s_waitcnt vmcnt(0)" ::: "memory");
#undef S1_STAGE
#undef S1_COMPUTE
#undef S1_PHASE

    int rmax = ce - rows0;
    float bgv[4], buv[4];
    int hc[4]; bool hok[4];
#pragma unroll
    for (int n = 0; n < 4; ++n) {
        hc[n] = h0 + wn * 64 + n * 16 + (lane & 15);
        hok[n] = hc[n] < DH;
        bgv[n] = hok[n] ? bg[e * DH + hc[n]] : 0.f;
        buv[n] = hok[n] ? bu[e * DH + hc[n]] : 0.f;
    }
#pragma unroll
    for (int m = 0; m < 4; ++m) {
#pragma unroll
        for (int r = 0; r < 4; ++r) {
            int rl = wm * 64 + m * 16 + (lane >> 4) * 4 + r;
            if (rl < rmax) {
                int rg = oe + rows0 + rl;
                float s = sc[rg];
                size_t rowb = (size_t)rg * DHP;
#pragma unroll
                for (int n = 0; n < 4; ++n) {
                    float v = 0.f;
                    if (hok[n]) {
                        float gv = accg[m][n][r] + bgv[n];
                        float uv = accu[m][n][r] + buv[n];
                        float sig = 1.0f / (1.0f + __expf(-gv));
                        v = s * gv * sig * uv;
                    } else if (hc[n] == DH) {
                        v = s;          // bias-fold: pairs with wd16 col 1376
                    }
                    inter[rowb + hc[n]] = f2bf(v);
                }
            }
        }
    }
}

// ============ stage-2: atomic-free pair-partial output; setprio removed ============
__global__ __launch_bounds__(256, 2) void k_stage2p(
    const u16* __restrict__ inter, const u16* __restrict__ wd16,
    const int* __restrict__ cnt, const int* __restrict__ off,
    u16* __restrict__ ypart)
{
    int e = blockIdx.x & 7;
    int ce = cnt[e];
    int rows0 = (blockIdx.x >> 3) * 128;
    if (rows0 >= ce) return;
    int oe = off[e];
    int o0 = blockIdx.y * 128;
    int tid = threadIdx.x;

    __shared__ u16 As0[128 * 32]; __shared__ u16 As1[128 * 32];
    __shared__ u16 Bs0[128 * 32]; __shared__ u16 Bs1[128 * 32];

    int swz = ((tid & 3) ^ ((tid >> 3) & 3)) * 8;
    const u16* ab0; const u16* ab1; const u16* bb0; const u16* bb1;
    {
        int rl0 = tid >> 2, rl1 = 64 + (tid >> 2);
        int ar0 = min(oe + rows0 + rl0, NPAIR - 1);
        int ar1 = min(oe + rows0 + rl1, NPAIR - 1);
        ab0 = inter + (size_t)ar0 * DHP + swz;
        ab1 = inter + (size_t)ar1 * DHP + swz;
        bb0 = wd16 + ((size_t)e * DO + (o0 + rl0)) * DHP + swz;
        bb1 = wd16 + ((size_t)e * DO + (o0 + rl1)) * DHP + swz;
    }

    int wid = tid >> 6, lane = tid & 63;
    int ldsw = wid * 512;
    int wm = wid >> 1, wn = wid & 1;
    int rA = wm * 64 + (lane & 15);
    int rB = wn * 64 + (lane & 15);
    int colb = (((lane >> 4) ^ ((lane >> 1) & 3)) & 3) * 8;

    f32x4 acc[4][4];
    f32x4 vz = {0.f, 0.f, 0.f, 0.f};
#pragma unroll
    for (int m = 0; m < 4; ++m)
#pragma unroll
        for (int n = 0; n < 4; ++n) acc[m][n] = vz;

#define S2_STAGE(A_, B_, K0)                                       \
    do {                                                           \
        gload16(ab0 + (K0), &A_[ldsw]);                            \
        gload16(ab1 + (K0), &A_[2048 + ldsw]);                     \
        gload16(bb0 + (K0), &B_[ldsw]);                            \
        gload16(bb1 + (K0), &B_[2048 + ldsw]);                     \
    } while (0)

#define S2_COMPUTE(A_, B_)                                         \
    do {                                                           \
        bf16x8 a[4], b[4];                                         \
        _Pragma("unroll")                                          \
        for (int m = 0; m < 4; ++m)                                \
            a[m] = *(const bf16x8*)&A_[(rA + m * 16) * 32 + colb]; \
        _Pragma("unroll")                                          \
        for (int n = 0; n < 4; ++n)                                \
            b[n] = *(const bf16x8*)&B_[(rB + n * 16) * 32 + colb]; \
        _Pragma("unroll")                                          \
        for (int m = 0; m < 4; ++m)                                \
            _Pragma("unroll")                                      \
            for (int n = 0; n < 4; ++n)                            \
                acc[m][n] = __builtin_amdgcn_mfma_f32_16x16x32_bf16(a[m], b[n], acc[m][n], 0, 0, 0); \
    } while (0)

    const int NT = DHP / 32;       // 44, even
    S2_STAGE(As0, Bs0, 0);
    S2_STAGE(As1, Bs1, 32);

    for (int kt = 0; kt < NT - 2; kt += 2) {
        asm volatile("s_waitcnt vmcnt(4)" ::: "memory");
        __builtin_amdgcn_s_barrier();
        MEMFENCE();
        S2_COMPUTE(As0, Bs0);
        __builtin_amdgcn_s_barrier();
        MEMFENCE();
        S2_STAGE(As0, Bs0, (kt + 2) * 32);
        asm volatile("s_waitcnt vmcnt(4)" ::: "memory");
        __builtin_amdgcn_s_barrier();
        MEMFENCE();
        S2_COMPUTE(As1, Bs1);
        __builtin_amdgcn_s_barrier();
        MEMFENCE();
        S2_STAGE(As1, Bs1, (kt + 3) * 32);
    }
    asm volatile("s_waitcnt vmcnt(4)" ::: "memory");
    __builtin_amdgcn_s_barrier();
    MEMFENCE();
    S2_COMPUTE(As0, Bs0);
    asm volatile("s_waitcnt vmcnt(0)" ::: "memory");
    __builtin_amdgcn_s_barrier();
    MEMFENCE();
    S2_COMPUTE(As1, Bs1);
#undef S2_STAGE
#undef S2_COMPUTE

    int rmax = ce - rows0;
#pragma unroll
    for (int m = 0; m < 4; ++m) {
#pragma unroll
        for (int r = 0; r < 4; ++r) {
            int rl = wm * 64 + m * 16 + (lane >> 4) * 4 + r;
            if (rl >= rmax) continue;
            size_t rowb = (size_t)(oe + rows0 + rl) * DO + o0 + wn * 64 + (lane & 15);
#pragma unroll
            for (int n = 0; n < 4; ++n)
                __builtin_nontemporal_store(f2bf(acc[m][n][r]), &ypart[rowb + n * 16]);
        }
    }
}

// ---------------- reduce: y[t] = ypart[p0] + ypart[p1] (NT stores) ----------------
__global__ __launch_bounds__(256) void k_reduce(
    const u16* __restrict__ ypart, const int* __restrict__ tpos,
    float* __restrict__ y)
{
    int t = blockIdx.x, tid = threadIdx.x;
    int p0 = tpos[2 * t], p1 = tpos[2 * t + 1];
    int c = tid * 16;
    const u16* r0 = ypart + (size_t)p0 * DO + c;
    const u16* r1 = ypart + (size_t)p1 * DO + c;
    float* yr = y + (size_t)t * DO + c;
    u32x4 a0 = *(const u32x4*)r0, a1 = *(const u32x4*)(r0 + 8);
    u32x4 b0 = *(const u32x4*)r1, b1 = *(const u32x4*)(r1 + 8);
    uint32_t ua[8] = {a0.x, a0.y, a0.z, a0.w, a1.x, a1.y, a1.z, a1.w};
    uint32_t ub[8] = {b0.x, b0.y, b0.z, b0.w, b1.x, b1.y, b1.z, b1.w};
#pragma unroll
    for (int j = 0; j < 8; ++j) {
        __builtin_nontemporal_store(bflo(ua[j]) + bflo(ub[j]), &yr[2 * j]);
        __builtin_nontemporal_store(bfhi(ua[j]) + bfhi(ub[j]), &yr[2 * j + 1]);
    }
}

// ---------------- host launch ----------------
extern "C" void kernel_launch(void* const* d_in, const int* in_sizes, int n_in,
                              void* d_out, int out_size, void* d_ws, size_t ws_size,
                              hipStream_t stream)
{
    const float* x  = (const float*)d_in[0];
    const float* gw = (const float*)d_in[1];
    const float* wg = (const float*)d_in[2];
    const float* bg = (const float*)d_in[3];
    const float* wu = (const float*)d_in[4];
    const float* bu = (const float*)d_in[5];
    const float* wd = (const float*)d_in[6];
    const float* bd = (const float*)d_in[7];
    float* y = (float*)d_out;
    float* loss = y + (size_t)TN * DO;

    uint8_t* ws = (uint8_t*)d_ws;
    u16*   x16   = (u16*)(ws + 0);             // 33,554,432
    u16*   inter = (u16*)(ws + 33554432ull);   // 23,068,672 (stride DHP; col1376=score)
    u16*   wg16  = (u16*)(ws + 56623104ull);   // 90,177,536 (reused as ypart after stage1)
    u16*   wu16  = (u16*)(ws + 146800640ull);  // 90,177,536
    u16*   wd16  = (u16*)(ws + 236978176ull);  // 92,274,688 (stride DHP; col1376=b_down)
    int*   tok   = (int*)(ws + 329252864ull);
    float* sc    = (float*)(ws + 329285632ull);
    int*   tke   = (int*)(ws + 329318400ull);  // expert ids, then pair positions
    float* tks   = (float*)(ws + 329351168ull);
    int*   misc  = (int*)(ws + 329383936ull);
    int* cnt = misc; int* fill = misc + 8; int* off = misc + 16;
    float* imp = (float*)(misc + 24);
    u16* ypart = wg16;                          // 67 MB needed; wg16 region is 90 MB

    hipMemsetAsync(misc, 0, 128, stream);
    k_cvt_gate<<<70656, 256, 0, stream>>>(x, gw, wg, wu, wd, bd,
                                          x16, wg16, wu16, wd16,
                                          tke, tks, cnt, imp);
    k_scatter_fin<<<16, 256, 0, stream>>>(tke, tks, cnt, imp, off, fill, tok, sc, loss);
    k_stage1g<<<dim3(256, 11), 256, 0, stream>>>(x16, wg16, wu16, bg, bu, cnt, off, tok, sc, inter);
    k_stage2p<<<dim3(256, 32), 256, 0, stream>>>(inter, wd16, cnt, off, ypart);
    k_reduce<<<TN, 256, 0, stream>>>(ypart, tke, y);
}